// Round 2
// baseline (6709.355 us; speedup 1.0000x reference)
//
#include <hip/hip_runtime.h>
#include <hip/hip_bf16.h>
#include <cstdint>
#include <cstddef>
#include <math.h>

using bf16 = __hip_bfloat16;
typedef __bf16 bf16x8 __attribute__((ext_vector_type(8)));
typedef float f32x4 __attribute__((ext_vector_type(4)));

// ---------------- constants ----------------
static constexpr int NHEAD = 12;
static constexpr int NTOK  = 211;   // 210 patches + cls
static constexpr int DEPTH = 11;

// ---------------- global->LDS direct load ----------------
static __device__ __forceinline__ void gload_lds16(const bf16* g, bf16* lds) {
  __builtin_amdgcn_global_load_lds(
      (const __attribute__((address_space(1))) uint32_t*)g,
      (__attribute__((address_space(3))) uint32_t*)lds,
      16, 0, 0);
}

// ---------------- TN GEMM: C[M,N] = A[M,K] * Bt[N,K]^T (+bias, gelu, residual) ----------------
// 128x128 tile, BK=32, 4 waves, each wave 64x64 via 4x4 16x16x32 MFMA frags.
template <bool GELU, bool RES, typename CT>
__global__ __launch_bounds__(256) void gemm_tn(
    const bf16* __restrict__ A, const bf16* __restrict__ Bt,
    const float* __restrict__ bias, const float* __restrict__ res,
    CT* __restrict__ C, int M, int N, int K)
{
  __shared__ bf16 As[128 * 32];
  __shared__ bf16 Bs[128 * 32];
  const int tid = threadIdx.x;
  const int w = tid >> 6;
  const int l = tid & 63;
  const int lr = l & 15, lg = l >> 4;
  const int bm0 = blockIdx.x * 128;
  const int bn0 = blockIdx.y * 128;
  const int wr = (w >> 1) * 64, wc = (w & 1) * 64;

  f32x4 acc[4][4];
#pragma unroll
  for (int i = 0; i < 4; ++i)
#pragma unroll
    for (int j = 0; j < 4; ++j) acc[i][j] = f32x4{0.f, 0.f, 0.f, 0.f};

  // staging: chunk c = (w*2+i)*64 + l ; row = c>>2 (of 128), piece = c&3 (8 bf16 each)
  const int c0 = (w * 2 + 0) * 64 + l;
  const int c1 = (w * 2 + 1) * 64 + l;
  int ar0 = bm0 + (c0 >> 2); if (ar0 >= M) ar0 = M - 1;
  int ar1 = bm0 + (c1 >> 2); if (ar1 >= M) ar1 = M - 1;
  const size_t aoff0 = (size_t)ar0 * K + (c0 & 3) * 8;
  const size_t aoff1 = (size_t)ar1 * K + (c1 & 3) * 8;
  const size_t boff0 = (size_t)(bn0 + (c0 >> 2)) * K + (c0 & 3) * 8;
  const size_t boff1 = (size_t)(bn0 + (c1 >> 2)) * K + (c1 & 3) * 8;
  bf16* const ad0 = As + (w * 2 + 0) * 512;
  bf16* const ad1 = As + (w * 2 + 1) * 512;
  bf16* const bd0 = Bs + (w * 2 + 0) * 512;
  bf16* const bd1 = Bs + (w * 2 + 1) * 512;

  for (int k0 = 0; k0 < K; k0 += 32) {
    gload_lds16(A + aoff0 + k0, ad0);
    gload_lds16(A + aoff1 + k0, ad1);
    gload_lds16(Bt + boff0 + k0, bd0);
    gload_lds16(Bt + boff1 + k0, bd1);
    __syncthreads();
    bf16x8 af[4], bfr[4];
#pragma unroll
    for (int mi = 0; mi < 4; ++mi)
      af[mi] = *reinterpret_cast<const bf16x8*>(As + (wr + mi * 16 + lr) * 32 + lg * 8);
#pragma unroll
    for (int ni = 0; ni < 4; ++ni)
      bfr[ni] = *reinterpret_cast<const bf16x8*>(Bs + (wc + ni * 16 + lr) * 32 + lg * 8);
#pragma unroll
    for (int mi = 0; mi < 4; ++mi)
#pragma unroll
      for (int ni = 0; ni < 4; ++ni)
        acc[mi][ni] = __builtin_amdgcn_mfma_f32_16x16x32_bf16(af[mi], bfr[ni], acc[mi][ni], 0, 0, 0);
    __syncthreads();
  }

#pragma unroll
  for (int mi = 0; mi < 4; ++mi) {
#pragma unroll
    for (int ni = 0; ni < 4; ++ni) {
      const int col = bn0 + wc + ni * 16 + lr;
      const float bv = bias[col];
#pragma unroll
      for (int r = 0; r < 4; ++r) {
        const int row = bm0 + wr + mi * 16 + lg * 4 + r;
        if (row < M) {
          float v = acc[mi][ni][r] + bv;
          if constexpr (GELU) v = 0.5f * v * (1.f + erff(v * 0.7071067811865475f));
          if constexpr (RES) v += res[(size_t)row * N + col];
          if constexpr (sizeof(CT) == 4) {
            C[(size_t)row * N + col] = v;
          } else {
            C[(size_t)row * N + col] = __float2bfloat16(v);
          }
        }
      }
    }
  }
}

// ---------------- fused attention: one block per (bb, head) ----------------
// qkv rows: (bb*ntok + tok) * 2304 ; q at h*64, k at 768+h*64, v at 1536+h*64
template <int NKF>  // NKF = padded token count / 16
__global__ __launch_bounds__(256) void attn_kernel(
    const bf16* __restrict__ qkv, bf16* __restrict__ ao, int ntok)
{
  constexpr int NPAD = NKF * 16;
  __shared__ bf16 Pl[4][16][NPAD];
  const int bb = blockIdx.x;
  const int h = blockIdx.y;
  const int tid = threadIdx.x;
  const int w = tid >> 6, l = tid & 63;
  const int lr = l & 15, lg = l >> 4;
  const __bf16* base = reinterpret_cast<const __bf16*>(qkv) + (size_t)bb * ntok * 2304 + h * 64;

  for (int qt = w; qt < NKF; qt += 4) {
    int qrow = qt * 16 + lr; if (qrow >= ntok) qrow = ntok - 1;
    const __bf16* qp = base + (size_t)qrow * 2304 + lg * 8;
    const bf16x8 qf0 = *reinterpret_cast<const bf16x8*>(qp);
    const bf16x8 qf1 = *reinterpret_cast<const bf16x8*>(qp + 32);

    // S = Q K^T  (D rows: query = lg*4+r, cols: key = kf*16+lr)
    f32x4 s[NKF];
#pragma unroll
    for (int kf = 0; kf < NKF; ++kf) {
      int krow = kf * 16 + lr; if (krow >= ntok) krow = ntok - 1;
      const __bf16* kp = base + (size_t)krow * 2304 + 768 + lg * 8;
      f32x4 a = f32x4{0.f, 0.f, 0.f, 0.f};
      a = __builtin_amdgcn_mfma_f32_16x16x32_bf16(qf0, *reinterpret_cast<const bf16x8*>(kp), a, 0, 0, 0);
      a = __builtin_amdgcn_mfma_f32_16x16x32_bf16(qf1, *reinterpret_cast<const bf16x8*>(kp + 32), a, 0, 0, 0);
      s[kf] = a;
    }

    // softmax per query row (16-lane group holds one row's cols per kf)
    float rs[4];
#pragma unroll
    for (int r = 0; r < 4; ++r) {
      float mx = -1e30f;
#pragma unroll
      for (int kf = 0; kf < NKF; ++kf)
        if (kf * 16 + lr < ntok) mx = fmaxf(mx, s[kf][r]);
#pragma unroll
      for (int d = 1; d < 16; d <<= 1) mx = fmaxf(mx, __shfl_xor(mx, d));
      float sum = 0.f;
#pragma unroll
      for (int kf = 0; kf < NKF; ++kf) {
        float p = 0.f;
        if (kf * 16 + lr < ntok) p = __expf((s[kf][r] - mx) * 0.125f);
        sum += p;
        Pl[w][lg * 4 + r][kf * 16 + lr] = __float2bfloat16(p);
      }
#pragma unroll
      for (int d = 1; d < 16; d <<= 1) sum += __shfl_xor(sum, d);
      rs[r] = sum;
    }

    // O = P V   (P from LDS in A-layout; V frags assembled scalar from global)
    f32x4 o[4];
#pragma unroll
    for (int ni = 0; ni < 4; ++ni) o[ni] = f32x4{0.f, 0.f, 0.f, 0.f};
    const __bf16* vbase = base + 1536;
#pragma unroll
    for (int ks = 0; ks < NPAD / 32; ++ks) {
      const bf16x8 pa = *reinterpret_cast<const bf16x8*>(&Pl[w][lr][ks * 32 + lg * 8]);
#pragma unroll
      for (int ni = 0; ni < 4; ++ni) {
        bf16x8 vb;
#pragma unroll
        for (int j = 0; j < 8; ++j) {
          int vk = ks * 32 + lg * 8 + j; if (vk >= ntok) vk = ntok - 1;
          vb[j] = vbase[(size_t)vk * 2304 + ni * 16 + lr];
        }
        o[ni] = __builtin_amdgcn_mfma_f32_16x16x32_bf16(pa, vb, o[ni], 0, 0, 0);
      }
    }
#pragma unroll
    for (int ni = 0; ni < 4; ++ni)
#pragma unroll
      for (int r = 0; r < 4; ++r) {
        int q = qt * 16 + lg * 4 + r;
        if (q < ntok) {
          float val = o[ni][r] / rs[r];
          ao[((size_t)bb * ntok + q) * 768 + h * 64 + ni * 16 + lr] = __float2bfloat16(val);
        }
      }
  }
}

// ---------------- layernorm: f32 in -> bf16 out, one wave per row ----------------
__global__ __launch_bounds__(256) void ln_kernel(
    const float* __restrict__ x, const float* __restrict__ g, const float* __restrict__ b,
    bf16* __restrict__ out, int Mrows)
{
  int row = blockIdx.x * 4 + (threadIdx.x >> 6);
  if (row >= Mrows) return;
  int l = threadIdx.x & 63;
  const float* xr = x + (size_t)row * 768;
  float v[12]; float s = 0.f;
#pragma unroll
  for (int i = 0; i < 12; ++i) { v[i] = xr[l + i * 64]; s += v[i]; }
#pragma unroll
  for (int d = 1; d < 64; d <<= 1) s += __shfl_xor(s, d);
  float mean = s * (1.f / 768.f);
  float s2 = 0.f;
#pragma unroll
  for (int i = 0; i < 12; ++i) { float t = v[i] - mean; s2 += t * t; }
#pragma unroll
  for (int d = 1; d < 64; d <<= 1) s2 += __shfl_xor(s2, d);
  float rstd = rsqrtf(s2 * (1.f / 768.f) + 1e-6f);
  bf16* orow = out + (size_t)row * 768;
#pragma unroll
  for (int i = 0; i < 12; ++i) {
    orow[l + i * 64] = __float2bfloat16((v[i] - mean) * rstd * g[l + i * 64] + b[l + i * 64]);
  }
}

// ---------------- head layernorm (row 0 of each sequence) -> output (f32) ----------------
__global__ __launch_bounds__(256) void ln_head_kernel(
    const float* __restrict__ x, int tokstride, const float* __restrict__ g,
    const float* __restrict__ b, float* __restrict__ out, int nbb, int mode)
{
  int bb = blockIdx.x * 4 + (threadIdx.x >> 6);
  if (bb >= nbb) return;
  int l = threadIdx.x & 63;
  const float* xr = x + (size_t)bb * tokstride * 768;
  float v[12]; float s = 0.f;
#pragma unroll
  for (int i = 0; i < 12; ++i) { v[i] = xr[l + i * 64]; s += v[i]; }
#pragma unroll
  for (int d = 1; d < 64; d <<= 1) s += __shfl_xor(s, d);
  float mean = s * (1.f / 768.f);
  float s2 = 0.f;
#pragma unroll
  for (int i = 0; i < 12; ++i) { float t = v[i] - mean; s2 += t * t; }
#pragma unroll
  for (int d = 1; d < 64; d <<= 1) s2 += __shfl_xor(s2, d);
  float rstd = rsqrtf(s2 * (1.f / 768.f) + 1e-6f);
  float scale = mode ? 0.25f : 1.f;
  int b_ = mode ? (bb & 63) : bb;
  int off = mode ? (1 + (bb >> 6)) * 768 : 0;
  float* orow = out + (size_t)b_ * 3840 + off;
#pragma unroll
  for (int i = 0; i < 12; ++i) {
    orow[l + i * 64] = ((v[i] - mean) * rstd * g[l + i * 64] + b[l + i * 64]) * scale;
  }
}

// ---------------- weight transpose (R,C) f32 -> (C,R) bf16 ----------------
__global__ __launch_bounds__(256) void transpose_k(
    const float* __restrict__ in, bf16* __restrict__ out, int R, int C)
{
  __shared__ float tile[32][33];
  int c0 = blockIdx.x * 32, r0 = blockIdx.y * 32;
  int tx = threadIdx.x & 31, ty = threadIdx.x >> 5;  // ty 0..7
#pragma unroll
  for (int i = 0; i < 4; ++i) {
    int r = ty + i * 8;
    tile[r][tx] = in[(size_t)(r0 + r) * C + c0 + tx];
  }
  __syncthreads();
#pragma unroll
  for (int i = 0; i < 4; ++i) {
    int c = ty + i * 8;
    out[(size_t)(c0 + c) * R + r0 + tx] = __float2bfloat16(tile[tx][c]);
  }
}

// ---------------- f32 -> bf16 cast ----------------
__global__ void cast_kernel(const float* __restrict__ in, bf16* __restrict__ out, int n)
{
  int idx = blockIdx.x * 256 + threadIdx.x;
  if (idx < n) out[idx] = __float2bfloat16(in[idx]);
}

// ---------------- patch im2col (f32 -> bf16) ----------------
__global__ void im2col_kernel(const float* __restrict__ x, bf16* __restrict__ pm)
{
  int idx = blockIdx.x * 256 + threadIdx.x;
  if (idx >= 13440 * 768) return;
  int k = idx % 768;
  int m = idx / 768;
  int b = m / 210, p = m % 210;
  int py = p / 10, px = p % 10;
  int c = k >> 8, ij = k & 255, i = ij >> 4, j = ij & 15;
  pm[idx] = __float2bfloat16(x[(((size_t)b * 3 + c) * 256 + py * 12 + i) * 128 + px * 12 + j]);
}

// ---------------- assemble t = [cls | patches] + pos + SIE*sie[cid] (f32) ----------------
__global__ void assemble_kernel(
    const bf16* __restrict__ y, const float* __restrict__ cls, const float* __restrict__ pos,
    const float* __restrict__ sie, const int* __restrict__ cids, float* __restrict__ tA)
{
  int idx = blockIdx.x * 256 + threadIdx.x;
  if (idx >= 13504 * 768) return;
  int d = idx % 768;
  int t = (idx / 768) % 211;
  int b = idx / (768 * 211);
  float v = pos[t * 768 + d] + 3.0f * sie[cids[b] * 768 + d];
  if (t == 0) v += cls[d];
  else v += __bfloat162float(y[((size_t)b * 210 + (t - 1)) * 768 + d]);
  tA[idx] = v;
}

// ---------------- gather the 4 shuffled segments into a 256-batch of 53 tokens ----------------
__global__ void gather_kernel(const float* __restrict__ tA, float* __restrict__ tB)
{
  int idx = blockIdx.x * 256 + threadIdx.x;
  if (idx >= 256 * 53 * 768) return;
  int d = idx % 768;
  int jj = (idx / 768) % 53;
  int bb = idx / (768 * 53);
  int i = bb >> 6, b = bb & 63;
  int src;
  if (jj == 0) src = 0;
  else {
    int jx = i * 52 + (jj - 1);
    int mm = (jx & 1) * 105 + (jx >> 1);
    src = (mm < 206) ? (5 + mm) : (1 + (mm - 206));
  }
  tB[idx] = tA[((size_t)b * 211 + src) * 768 + d];
}

// ---------------- host orchestration ----------------
struct BlkP {
  const float *ln1_g, *ln1_b, *qkv_w, *qkv_b, *proj_w, *proj_b;
  const float *ln2_g, *ln2_b, *fc1_w, *fc1_b, *fc2_w, *fc2_b;
};

extern "C" void kernel_launch(void* const* d_in, const int* in_sizes, int n_in,
                              void* d_out, int out_size, void* d_ws, size_t ws_size,
                              hipStream_t stream)
{
  (void)in_sizes; (void)n_in; (void)out_size; (void)ws_size;
  const float* xin   = (const float*)d_in[0];
  const int*   cids  = (const int*)  d_in[1];
  const float* convw = (const float*)d_in[2];
  const float* convb = (const float*)d_in[3];
  const float* cls   = (const float*)d_in[4];
  const float* pos   = (const float*)d_in[5];
  const float* sie   = (const float*)d_in[6];
  float* out = (float*)d_out;

  // workspace layout (bytes)
  char* ws = (char*)d_ws;
  bf16*  qkvT = (bf16*)(ws + 0);            // 2304x768 bf16 (also convw_bf slot)
  bf16*  projT = (bf16*)(ws + 3538944);     // 768x768
  bf16*  fc1T = (bf16*)(ws + 4718592);      // 3072x768
  bf16*  fc2T = (bf16*)(ws + 9437184);      // 768x3072
  float* tA   = (float*)(ws + 14155776);    // 13504x768 f32
  float* tB   = (float*)(ws + 55640064);    // 13568x768 f32
  bf16*  hb   = (bf16*)(ws + 97320960);     // 13568x768 bf16
  bf16*  big  = (bf16*)(ws + 118161408);    // qkv / mlp-mid / im2col (79.5MB)
  bf16*  ao   = (bf16*)(ws + 201523200);    // 13568x768 bf16

  dim3 blk(256);

  auto apply_block = [&](float* xbuf, const BlkP& p, int nb, int ntok_) {
    const int M = nb * ntok_;
    const int gm = (M + 127) / 128;
    transpose_k<<<dim3(2304 / 32, 768 / 32), blk, 0, stream>>>(p.qkv_w, qkvT, 768, 2304);
    transpose_k<<<dim3(768 / 32, 768 / 32), blk, 0, stream>>>(p.proj_w, projT, 768, 768);
    transpose_k<<<dim3(3072 / 32, 768 / 32), blk, 0, stream>>>(p.fc1_w, fc1T, 768, 3072);
    transpose_k<<<dim3(768 / 32, 3072 / 32), blk, 0, stream>>>(p.fc2_w, fc2T, 3072, 768);
    ln_kernel<<<dim3((M + 3) / 4), blk, 0, stream>>>(xbuf, p.ln1_g, p.ln1_b, hb, M);
    gemm_tn<false, false, bf16><<<dim3(gm, 2304 / 128), blk, 0, stream>>>(
        hb, qkvT, p.qkv_b, nullptr, big, M, 2304, 768);
    if (ntok_ == NTOK)
      attn_kernel<14><<<dim3(nb, NHEAD), blk, 0, stream>>>(big, ao, ntok_);
    else
      attn_kernel<4><<<dim3(nb, NHEAD), blk, 0, stream>>>(big, ao, ntok_);
    gemm_tn<false, true, float><<<dim3(gm, 768 / 128), blk, 0, stream>>>(
        ao, projT, p.proj_b, xbuf, xbuf, M, 768, 768);
    ln_kernel<<<dim3((M + 3) / 4), blk, 0, stream>>>(xbuf, p.ln2_g, p.ln2_b, hb, M);
    gemm_tn<true, false, bf16><<<dim3(gm, 3072 / 128), blk, 0, stream>>>(
        hb, fc1T, p.fc1_b, nullptr, big, M, 3072, 768);
    gemm_tn<false, true, float><<<dim3(gm, 768 / 128), blk, 0, stream>>>(
        big, fc2T, p.fc2_b, xbuf, xbuf, M, 768, 3072);
  };

  // 1) patch embed: im2col -> GEMM(conv) -> assemble
  {
    int total = 13440 * 768;
    im2col_kernel<<<dim3((total + 255) / 256), blk, 0, stream>>>(xin, big);
    int nw = 768 * 768;
    cast_kernel<<<dim3((nw + 255) / 256), blk, 0, stream>>>(convw, qkvT, nw);
    gemm_tn<false, false, bf16><<<dim3(105, 6), blk, 0, stream>>>(
        big, qkvT, convb, nullptr, ao, 13440, 768, 768);
    total = 13504 * 768;
    assemble_kernel<<<dim3((total + 255) / 256), blk, 0, stream>>>(ao, cls, pos, sie, cids, tA);
  }

  // 2) 11 stacked blocks (lead-dim DEPTH params)
  const float* bp[12];
  for (int i = 0; i < 12; ++i) bp[i] = (const float*)d_in[7 + i];
  for (int dd = 0; dd < DEPTH; ++dd) {
    BlkP p;
    p.ln1_g = bp[0] + dd * 768;                p.ln1_b = bp[1] + dd * 768;
    p.qkv_w = bp[2] + (size_t)dd * 768 * 2304; p.qkv_b = bp[3] + dd * 2304;
    p.proj_w = bp[4] + (size_t)dd * 768 * 768; p.proj_b = bp[5] + dd * 768;
    p.ln2_g = bp[6] + dd * 768;                p.ln2_b = bp[7] + dd * 768;
    p.fc1_w = bp[8] + (size_t)dd * 768 * 3072; p.fc1_b = bp[9] + dd * 3072;
    p.fc2_w = bp[10] + (size_t)dd * 3072 * 768; p.fc2_b = bp[11] + dd * 768;
    apply_block(tA, p, 64, NTOK);
  }

  // 3) b1 branch: f0 = LN(block(t))[:,0]
  hipMemcpyAsync(tB, tA, (size_t)13504 * 768 * 4, hipMemcpyDeviceToDevice, stream);
  {
    BlkP p;
    p.ln1_g = (const float*)d_in[19]; p.ln1_b = (const float*)d_in[20];
    p.qkv_w = (const float*)d_in[21]; p.qkv_b = (const float*)d_in[22];
    p.proj_w = (const float*)d_in[23]; p.proj_b = (const float*)d_in[24];
    p.ln2_g = (const float*)d_in[25]; p.ln2_b = (const float*)d_in[26];
    p.fc1_w = (const float*)d_in[27]; p.fc1_b = (const float*)d_in[28];
    p.fc2_w = (const float*)d_in[29]; p.fc2_b = (const float*)d_in[30];
    apply_block(tB, p, 64, NTOK);
    ln_head_kernel<<<dim3(16), blk, 0, stream>>>(
        tB, NTOK, (const float*)d_in[31], (const float*)d_in[32], out, 64, 0);
  }

  // 4) b2 branch: 4 shuffled segments batched as 256 sequences of 53 tokens
  {
    int total = 256 * 53 * 768;
    gather_kernel<<<dim3((total + 255) / 256), blk, 0, stream>>>(tA, tB);
    BlkP p;
    p.ln1_g = (const float*)d_in[33]; p.ln1_b = (const float*)d_in[34];
    p.qkv_w = (const float*)d_in[35]; p.qkv_b = (const float*)d_in[36];
    p.proj_w = (const float*)d_in[37]; p.proj_b = (const float*)d_in[38];
    p.ln2_g = (const float*)d_in[39]; p.ln2_b = (const float*)d_in[40];
    p.fc1_w = (const float*)d_in[41]; p.fc1_b = (const float*)d_in[42];
    p.fc2_w = (const float*)d_in[43]; p.fc2_b = (const float*)d_in[44];
    apply_block(tB, p, 256, 53);
    ln_head_kernel<<<dim3(64), blk, 0, stream>>>(
        tB, 53, (const float*)d_in[45], (const float*)d_in[46], out, 256, 1);
  }
}